// Round 1
// baseline (502.912 us; speedup 1.0000x reference)
//
#include <hip/hip_runtime.h>
#include <hip/hip_bf16.h>

// ---------------------------------------------------------------------------
// Transformer block: x + attn(LN1(x)) ; then x2 + proj(relu(fc(LN2(x2))))
// B=2, T=2048, C=1024, H=16, hd=64, MLP hidden 4096. All GEMMs bf16 MFMA.
// ---------------------------------------------------------------------------

typedef __bf16  bf16x8  __attribute__((ext_vector_type(8)));
typedef float   floatx4 __attribute__((ext_vector_type(4)));

#define T_LEN 2048
#define EMB   1024
#define NH    16
#define HD    64
#define HID   4096

// ---------------- transpose + cast: in fp32 [R,C] -> out bf16 [C,R] --------
__global__ void transpose_cast(const float* __restrict__ in,
                               __bf16* __restrict__ out, int R, int C) {
    __shared__ float tile[32][33];
    int bc = blockIdx.x * 32;   // col base (C dim)
    int br = blockIdx.y * 32;   // row base (R dim)
    int tx = threadIdx.x;       // 0..31
    int ty = threadIdx.y;       // 0..7
    for (int i = 0; i < 32; i += 8) {
        tile[ty + i][tx] = in[(size_t)(br + ty + i) * C + bc + tx];
    }
    __syncthreads();
    for (int i = 0; i < 32; i += 8) {
        int c = bc + ty + i, r = br + tx;
        out[(size_t)c * R + r] = (__bf16)tile[tx][ty + i];
    }
}

// ---------------- layernorm fp32 [M,1024] -> bf16 [M,1024] -----------------
__global__ __launch_bounds__(256)
void ln_kernel(const float* __restrict__ in, const float* __restrict__ sc,
               const float* __restrict__ sh, __bf16* __restrict__ out) {
    int row = blockIdx.x;
    const float* p = in + (size_t)row * EMB;
    int tid = threadIdx.x;
    int lane = tid & 63, wave = tid >> 6;
    float v[4];
    float s = 0.f, s2 = 0.f;
    for (int j = 0; j < 4; j++) {
        v[j] = p[tid + j * 256];
        s += v[j]; s2 += v[j] * v[j];
    }
    for (int m = 1; m < 64; m <<= 1) {
        s  += __shfl_xor(s, m);
        s2 += __shfl_xor(s2, m);
    }
    __shared__ float ssum[4], ssum2[4];
    if (lane == 0) { ssum[wave] = s; ssum2[wave] = s2; }
    __syncthreads();
    float tot  = ssum[0] + ssum[1] + ssum[2] + ssum[3];
    float tot2 = ssum2[0] + ssum2[1] + ssum2[2] + ssum2[3];
    float mean = tot * (1.f / EMB);
    float var  = tot2 * (1.f / EMB) - mean * mean;
    float rstd = rsqrtf(var + 1e-5f);
    for (int j = 0; j < 4; j++) {
        int c = tid + j * 256;
        out[(size_t)row * EMB + c] = (__bf16)((v[j] - mean) * rstd * sc[c] + sh[c]);
    }
}

// ---------------- bf16 MFMA GEMM: C = A[M,K] @ Bt[N,K]^T + bias ------------
// optional relu, optional fp32 residual, fp32 and/or bf16 outputs.
__global__ __launch_bounds__(256)
void gemm_bt(const __bf16* __restrict__ A, const __bf16* __restrict__ Bt,
             const float* __restrict__ bias, const float* __restrict__ res,
             float* __restrict__ outF, __bf16* __restrict__ outB,
             int M, int N, int K, int relu) {
    __shared__ __align__(16) __bf16 sA[128][40];
    __shared__ __align__(16) __bf16 sB[128][40];
    int tid  = threadIdx.x;
    int lane = tid & 63, wave = tid >> 6;
    int quad = lane >> 4, l16 = lane & 15;
    int bm = blockIdx.y * 128, bn = blockIdx.x * 128;
    int wm = (wave & 1) * 64, wn = (wave >> 1) * 64;
    floatx4 acc[4][4] = {};
    int srow = tid >> 2;          // 0..63
    int scol = (tid & 3) * 8;     // 0,8,16,24

    for (int kk = 0; kk < K; kk += 32) {
        __syncthreads();
        *(uint4*)&sA[srow][scol] =
            *(const uint4*)&A[(size_t)(bm + srow) * K + kk + scol];
        *(uint4*)&sA[srow + 64][scol] =
            *(const uint4*)&A[(size_t)(bm + srow + 64) * K + kk + scol];
        *(uint4*)&sB[srow][scol] =
            *(const uint4*)&Bt[(size_t)(bn + srow) * K + kk + scol];
        *(uint4*)&sB[srow + 64][scol] =
            *(const uint4*)&Bt[(size_t)(bn + srow + 64) * K + kk + scol];
        __syncthreads();
        bf16x8 af[4], bfr[4];
        for (int i = 0; i < 4; i++)
            af[i] = *(const bf16x8*)&sA[wm + i * 16 + l16][quad * 8];
        for (int j = 0; j < 4; j++)
            bfr[j] = *(const bf16x8*)&sB[wn + j * 16 + l16][quad * 8];
        for (int i = 0; i < 4; i++)
            for (int j = 0; j < 4; j++)
                acc[i][j] = __builtin_amdgcn_mfma_f32_16x16x32_bf16(
                    af[i], bfr[j], acc[i][j], 0, 0, 0);
    }

    for (int i = 0; i < 4; i++) {
        int row0 = bm + wm + i * 16 + quad * 4;
        for (int j = 0; j < 4; j++) {
            int col = bn + wn + j * 16 + l16;
            float bv = bias[col];
            for (int r = 0; r < 4; r++) {
                size_t idx = (size_t)(row0 + r) * N + col;
                float c = acc[i][j][r] + bv;
                if (relu) c = fmaxf(c, 0.f);
                if (res)  c += res[idx];
                if (outF) outF[idx] = c;
                if (outB) outB[idx] = (__bf16)c;
            }
        }
    }
}

// ---------------- flash attention ------------------------------------------
// qkv bf16 [B*T, 3072] (q|k|v each 1024 = 16 heads * 64)
// out: x2 = x + attn_out, fp32 [B*T, 1024]
// grid: (T/128, B*NH), block 256 (4 waves, 32 q-rows per wave)
__global__ __launch_bounds__(256)
void attn_kernel(const __bf16* __restrict__ qkv, const float* __restrict__ x,
                 float* __restrict__ x2) {
    __shared__ __align__(16) __bf16 sK[64][72];
    __shared__ __align__(16) __bf16 sVt[64][72];
    __shared__ __align__(16) __bf16 sP[4][32][72];
    int tid  = threadIdx.x;
    int lane = tid & 63, wave = tid >> 6;
    int quad = lane >> 4, l16 = lane & 15;
    int qb = blockIdx.x;
    int bh = blockIdx.y;
    int h  = bh & (NH - 1);
    int b  = bh >> 4;
    size_t rowbase = (size_t)b * T_LEN;
    int qrow = qb * 128 + wave * 32;

    // Q fragments in registers (A-operand layout)
    bf16x8 qf[2][2];
    for (int it = 0; it < 2; it++)
        for (int ks = 0; ks < 2; ks++)
            qf[it][ks] = *(const bf16x8*)&qkv[(rowbase + qrow + it * 16 + l16) * 3072
                                             + h * HD + ks * 32 + quad * 8];

    floatx4 o[2][4] = {};
    float mrow[2][4], lrow[2][4];
    for (int it = 0; it < 2; it++)
        for (int r = 0; r < 4; r++) { mrow[it][r] = -1e30f; lrow[it][r] = 0.f; }

    int ntiles = qb * 2 + 2;
    for (int kt = 0; kt < ntiles; kt++) {
        int k0 = kt * 64;
        __syncthreads();
        // stage K [key][hd] and V transposed [hd][key]
        for (int p = 0; p < 2; p++) {
            int idx = p * 256 + tid;          // 0..511
            int key = idx >> 3, c8 = (idx & 7) * 8;
            size_t gr = (rowbase + k0 + key) * 3072 + h * HD + c8;
            *(uint4*)&sK[key][c8] = *(const uint4*)&qkv[gr + 1024];
            bf16x8 vv = *(const bf16x8*)&qkv[gr + 2048];
            for (int j = 0; j < 8; j++) sVt[c8 + j][key] = vv[j];
        }
        __syncthreads();

        // S = Q K^T  (fp32 acc)
        floatx4 s_acc[2][4] = {};
        for (int jt = 0; jt < 4; jt++) {
            for (int ks = 0; ks < 2; ks++) {
                bf16x8 kf = *(const bf16x8*)&sK[jt * 16 + l16][ks * 32 + quad * 8];
                for (int it = 0; it < 2; it++)
                    s_acc[it][jt] = __builtin_amdgcn_mfma_f32_16x16x32_bf16(
                        qf[it][ks], kf, s_acc[it][jt], 0, 0, 0);
            }
        }

        // scale + causal mask + online softmax
        for (int it = 0; it < 2; it++) {
            int tq0 = qrow + it * 16 + quad * 4;
            float rmax[4] = {-1e30f, -1e30f, -1e30f, -1e30f};
            for (int jt = 0; jt < 4; jt++) {
                int key = k0 + jt * 16 + l16;
                for (int r = 0; r < 4; r++) {
                    float sv = s_acc[it][jt][r] * 0.125f;
                    sv = (key <= tq0 + r) ? sv : -1e30f;
                    s_acc[it][jt][r] = sv;
                    rmax[r] = fmaxf(rmax[r], sv);
                }
            }
            for (int r = 0; r < 4; r++) {
                float m = rmax[r];
                m = fmaxf(m, __shfl_xor(m, 1));
                m = fmaxf(m, __shfl_xor(m, 2));
                m = fmaxf(m, __shfl_xor(m, 4));
                m = fmaxf(m, __shfl_xor(m, 8));
                float mnew  = fmaxf(mrow[it][r], m);
                float alpha = __expf(mrow[it][r] - mnew);
                mrow[it][r] = mnew;
                lrow[it][r] *= alpha;
                for (int jt2 = 0; jt2 < 4; jt2++) o[it][jt2][r] *= alpha;
            }
            for (int r = 0; r < 4; r++) {
                float rsum = 0.f;
                for (int jt = 0; jt < 4; jt++) {
                    float pv = __expf(s_acc[it][jt][r] - mrow[it][r]);
                    s_acc[it][jt][r] = pv;
                    rsum += pv;
                }
                rsum += __shfl_xor(rsum, 1);
                rsum += __shfl_xor(rsum, 2);
                rsum += __shfl_xor(rsum, 4);
                rsum += __shfl_xor(rsum, 8);
                lrow[it][r] += rsum;
            }
            for (int jt = 0; jt < 4; jt++)
                for (int r = 0; r < 4; r++)
                    sP[wave][it * 16 + quad * 4 + r][jt * 16 + l16] =
                        (__bf16)s_acc[it][jt][r];
        }
        __syncthreads();   // P write -> A-frag read (also orders vs next staging)

        // O += P V
        for (int kp = 0; kp < 2; kp++) {
            bf16x8 pf[2];
            for (int it = 0; it < 2; it++)
                pf[it] = *(const bf16x8*)&sP[wave][it * 16 + l16][kp * 32 + quad * 8];
            for (int jt2 = 0; jt2 < 4; jt2++) {
                bf16x8 vf = *(const bf16x8*)&sVt[jt2 * 16 + l16][kp * 32 + quad * 8];
                for (int it = 0; it < 2; it++)
                    o[it][jt2] = __builtin_amdgcn_mfma_f32_16x16x32_bf16(
                        pf[it], vf, o[it][jt2], 0, 0, 0);
            }
        }
    }

    // epilogue: x2 = x + O / l
    for (int it = 0; it < 2; it++) {
        for (int jt2 = 0; jt2 < 4; jt2++) {
            for (int r = 0; r < 4; r++) {
                int tq  = qrow + it * 16 + quad * 4 + r;
                int col = h * HD + jt2 * 16 + l16;
                size_t gi = (rowbase + tq) * EMB + col;
                x2[gi] = x[gi] + o[it][jt2][r] / lrow[it][r];
            }
        }
    }
}

// ---------------------------------------------------------------------------
extern "C" void kernel_launch(void* const* d_in, const int* in_sizes, int n_in,
                              void* d_out, int out_size, void* d_ws, size_t ws_size,
                              hipStream_t stream) {
    const float* x      = (const float*)d_in[0];
    const float* ln1_s  = (const float*)d_in[1];
    const float* ln1_b  = (const float*)d_in[2];
    const float* w_qkv  = (const float*)d_in[3];
    const float* b_qkv  = (const float*)d_in[4];
    const float* ln2_s  = (const float*)d_in[5];
    const float* ln2_b  = (const float*)d_in[6];
    const float* w_fc   = (const float*)d_in[7];
    const float* b_fc   = (const float*)d_in[8];
    const float* w_proj = (const float*)d_in[9];
    const float* b_proj = (const float*)d_in[10];
    float* out = (float*)d_out;

    const int M = 2 * T_LEN;  // 4096 rows
    char* ws = (char*)d_ws;
    size_t off = 0;
    auto alloc = [&](size_t bytes) {
        void* p = ws + off; off += (bytes + 255) & ~(size_t)255; return p;
    };
    __bf16* wqkv_t = (__bf16*)alloc((size_t)3072 * 1024 * 2);
    __bf16* wfc_t  = (__bf16*)alloc((size_t)4096 * 1024 * 2);
    __bf16* wpj_t  = (__bf16*)alloc((size_t)1024 * 4096 * 2);
    __bf16* h1     = (__bf16*)alloc((size_t)M * 1024 * 2);
    __bf16* qkvb   = (__bf16*)alloc((size_t)M * 3072 * 2);
    float*  x2     = (float*) alloc((size_t)M * 1024 * 4);
    __bf16* h2     = (__bf16*)alloc((size_t)M * 1024 * 2);
    __bf16* hfc    = (__bf16*)alloc((size_t)M * 4096 * 2);

    dim3 tb(32, 8);
    transpose_cast<<<dim3(3072 / 32, 1024 / 32), tb, 0, stream>>>(w_qkv, wqkv_t, 1024, 3072);
    transpose_cast<<<dim3(4096 / 32, 1024 / 32), tb, 0, stream>>>(w_fc,  wfc_t,  1024, 4096);
    transpose_cast<<<dim3(1024 / 32, 4096 / 32), tb, 0, stream>>>(w_proj, wpj_t, 4096, 1024);

    ln_kernel<<<M, 256, 0, stream>>>(x, ln1_s, ln1_b, h1);

    // qkv = LN1(x) @ w_qkv + b_qkv   -> bf16
    gemm_bt<<<dim3(3072 / 128, M / 128), 256, 0, stream>>>(
        h1, wqkv_t, b_qkv, nullptr, nullptr, qkvb, M, 3072, 1024, 0);

    // x2 = x + attention(qkv)
    attn_kernel<<<dim3(T_LEN / 128, 2 * NH), 256, 0, stream>>>(qkvb, x, x2);

    ln_kernel<<<M, 256, 0, stream>>>(x2, ln2_s, ln2_b, h2);

    // hfc = relu(h2 @ w_fc + b_fc)  -> bf16
    gemm_bt<<<dim3(4096 / 128, M / 128), 256, 0, stream>>>(
        h2, wfc_t, b_fc, nullptr, nullptr, hfc, M, 4096, 1024, 1);

    // out = x2 + hfc @ w_proj + b_proj  -> fp32
    gemm_bt<<<dim3(1024 / 128, M / 128), 256, 0, stream>>>(
        hfc, wpj_t, b_proj, x2, out, nullptr, M, 1024, 4096, 0);
}

// Round 2
// 449.007 us; speedup vs baseline: 1.1201x; 1.1201x over previous
//
#include <hip/hip_runtime.h>
#include <hip/hip_bf16.h>

// ---------------------------------------------------------------------------
// Transformer block: x + attn(LN1(x)) ; then x2 + proj(relu(fc(LN2(x2))))
// B=2, T=2048, C=1024, H=16, hd=64, MLP hidden 4096. All GEMMs bf16 MFMA.
// R2: attn restructured (64-row q tiles, 1024 blocks, swizzled sVt, mask only
//     diag tiles); GEMM staging via global_load_lds width=16 (m97 pattern).
// ---------------------------------------------------------------------------

typedef __bf16  bf16x8  __attribute__((ext_vector_type(8)));
typedef float   floatx4 __attribute__((ext_vector_type(4)));

#define T_LEN 2048
#define EMB   1024
#define NH    16
#define HD    64
#define HID   4096

#define GLOBAL_LOAD_LDS16(gp, lp) \
    __builtin_amdgcn_global_load_lds( \
        (const __attribute__((address_space(1))) void*)(gp), \
        (__attribute__((address_space(3))) void*)(lp), 16, 0, 0)

// ---------------- transpose + cast: in fp32 [R,C] -> out bf16 [C,R] --------
__global__ void transpose_cast(const float* __restrict__ in,
                               __bf16* __restrict__ out, int R, int C) {
    __shared__ float tile[32][33];
    int bc = blockIdx.x * 32;
    int br = blockIdx.y * 32;
    int tx = threadIdx.x;
    int ty = threadIdx.y;
    for (int i = 0; i < 32; i += 8) {
        tile[ty + i][tx] = in[(size_t)(br + ty + i) * C + bc + tx];
    }
    __syncthreads();
    for (int i = 0; i < 32; i += 8) {
        int c = bc + ty + i, r = br + tx;
        out[(size_t)c * R + r] = (__bf16)tile[tx][ty + i];
    }
}

// ---------------- layernorm fp32 [M,1024] -> bf16 [M,1024] -----------------
__global__ __launch_bounds__(256)
void ln_kernel(const float* __restrict__ in, const float* __restrict__ sc,
               const float* __restrict__ sh, __bf16* __restrict__ out) {
    int row = blockIdx.x;
    const float* p = in + (size_t)row * EMB;
    int tid = threadIdx.x;
    int lane = tid & 63, wave = tid >> 6;
    float v[4];
    float s = 0.f, s2 = 0.f;
    for (int j = 0; j < 4; j++) {
        v[j] = p[tid + j * 256];
        s += v[j]; s2 += v[j] * v[j];
    }
    for (int m = 1; m < 64; m <<= 1) {
        s  += __shfl_xor(s, m);
        s2 += __shfl_xor(s2, m);
    }
    __shared__ float ssum[4], ssum2[4];
    if (lane == 0) { ssum[wave] = s; ssum2[wave] = s2; }
    __syncthreads();
    float tot  = ssum[0] + ssum[1] + ssum[2] + ssum[3];
    float tot2 = ssum2[0] + ssum2[1] + ssum2[2] + ssum2[3];
    float mean = tot * (1.f / EMB);
    float var  = tot2 * (1.f / EMB) - mean * mean;
    float rstd = rsqrtf(var + 1e-5f);
    for (int j = 0; j < 4; j++) {
        int c = tid + j * 256;
        out[(size_t)row * EMB + c] = (__bf16)((v[j] - mean) * rstd * sc[c] + sh[c]);
    }
}

// ---------------- bf16 MFMA GEMM: C = A[M,K] @ Bt[N,K]^T + bias ------------
// m97 structure: unpadded LDS, global_load_lds dwordx4 staging.
__global__ __launch_bounds__(256)
void gemm_bt(const __bf16* __restrict__ A, const __bf16* __restrict__ Bt,
             const float* __restrict__ bias, const float* __restrict__ res,
             float* __restrict__ outF, __bf16* __restrict__ outB,
             int M, int N, int K, int relu) {
    __shared__ __align__(16) __bf16 sA[128][32];
    __shared__ __align__(16) __bf16 sB[128][32];
    int tid  = threadIdx.x;
    int lane = tid & 63, wave = tid >> 6;
    int quad = lane >> 4, l16 = lane & 15;
    int bm = blockIdx.y * 128, bn = blockIdx.x * 128;
    int wm = (wave & 1) * 64, wn = (wave >> 1) * 64;
    floatx4 acc[4][4] = {};

    // staging: wave w covers segments [2w, 2w+1]; seg = 16 rows x 32 cols.
    // lane L -> row seg*16 + L/4, col (L&3)*8; LDS dst = base + L*16 (HW).
    int seg = wave * 2;
    int srow = seg * 16 + (lane >> 2);
    int scol = (lane & 3) * 8;
    const __bf16* gA0 = &A[(size_t)(bm + srow) * K + scol];
    const __bf16* gB0 = &Bt[(size_t)(bn + srow) * K + scol];
    __bf16* lA0 = &sA[seg * 16][0];
    __bf16* lB0 = &sB[seg * 16][0];

    for (int kk = 0; kk < K; kk += 32) {
        __syncthreads();
        GLOBAL_LOAD_LDS16(gA0 + kk, lA0);
        GLOBAL_LOAD_LDS16(gA0 + kk + (size_t)16 * K, lA0 + 16 * 32);
        GLOBAL_LOAD_LDS16(gB0 + kk, lB0);
        GLOBAL_LOAD_LDS16(gB0 + kk + (size_t)16 * K, lB0 + 16 * 32);
        __syncthreads();
        bf16x8 af[4], bfr[4];
        for (int i = 0; i < 4; i++)
            af[i] = *(const bf16x8*)&sA[wm + i * 16 + l16][quad * 8];
        for (int j = 0; j < 4; j++)
            bfr[j] = *(const bf16x8*)&sB[wn + j * 16 + l16][quad * 8];
        for (int i = 0; i < 4; i++)
            for (int j = 0; j < 4; j++)
                acc[i][j] = __builtin_amdgcn_mfma_f32_16x16x32_bf16(
                    af[i], bfr[j], acc[i][j], 0, 0, 0);
    }

    for (int i = 0; i < 4; i++) {
        int row0 = bm + wm + i * 16 + quad * 4;
        for (int j = 0; j < 4; j++) {
            int col = bn + wn + j * 16 + l16;
            float bv = bias[col];
            for (int r = 0; r < 4; r++) {
                size_t idx = (size_t)(row0 + r) * N + col;
                float c = acc[i][j][r] + bv;
                if (relu) c = fmaxf(c, 0.f);
                if (res)  c += res[idx];
                if (outF) outF[idx] = c;
                if (outB) outB[idx] = (__bf16)c;
            }
        }
    }
}

// ---------------- flash attention ------------------------------------------
// qkv bf16 [B*T, 3072]; out x2 = x + attn_out (fp32).
// grid: (32 qtiles, B*NH), block 256; wave handles 16 q-rows; KV tiles of 64.
// sVt stored XOR-swizzled: logical (d,key) at col ((key>>3)^(d>>3))*8+(key&7).
__global__ __launch_bounds__(256)
void attn_kernel(const __bf16* __restrict__ qkv, const float* __restrict__ x,
                 float* __restrict__ x2) {
    __shared__ __align__(16) __bf16 sK[64][72];
    __shared__ __align__(16) __bf16 sVt[64][72];
    __shared__ __align__(16) __bf16 sP[4][16][72];
    int tid  = threadIdx.x;
    int lane = tid & 63, wave = tid >> 6;
    int quad = lane >> 4, l16 = lane & 15;
    int qx = blockIdx.x;
    int qb = (qx & 1) ? (31 - (qx >> 1)) : (qx >> 1);   // load-balance pairing
    int bh = blockIdx.y;
    int h  = bh & (NH - 1);
    int b  = bh >> 4;
    size_t rowbase = (size_t)b * T_LEN;
    int qrow = qb * 64 + wave * 16;

    bf16x8 qf[2];
    for (int ks = 0; ks < 2; ks++)
        qf[ks] = *(const bf16x8*)&qkv[(rowbase + qrow + l16) * 3072
                                      + h * HD + ks * 32 + quad * 8];

    floatx4 o[4] = {};
    float mrow[4], lrow[4];
    for (int r = 0; r < 4; r++) { mrow[r] = -1e30f; lrow[r] = 0.f; }

    int ntiles = qb + 1;
    for (int kt = 0; kt < ntiles; kt++) {
        int k0 = kt * 64;
        __syncthreads();   // prior iter's sK/sVt reads done before overwrite
        for (int p = 0; p < 2; p++) {
            int idx = p * 256 + tid;
            int key = idx >> 3;           // 0..63
            int m8  = idx & 7;
            int c8  = m8 * 8;
            size_t gr = (rowbase + k0 + key) * 3072 + h * HD + c8;
            *(uint4*)&sK[key][c8] = *(const uint4*)&qkv[gr + 1024];
            bf16x8 vv = *(const bf16x8*)&qkv[gr + 2048];
            int pc = (((key >> 3) ^ m8) << 3) | (key & 7);
            for (int j = 0; j < 8; j++) sVt[c8 + j][pc] = vv[j];
        }
        __syncthreads();

        // S = Q K^T
        floatx4 s_acc[4] = {};
        for (int jt = 0; jt < 4; jt++)
            for (int ks = 0; ks < 2; ks++) {
                bf16x8 kf = *(const bf16x8*)&sK[jt * 16 + l16][ks * 32 + quad * 8];
                s_acc[jt] = __builtin_amdgcn_mfma_f32_16x16x32_bf16(
                    qf[ks], kf, s_acc[jt], 0, 0, 0);
            }

        // scale + (diag-only) mask + online softmax
        int tq0 = qrow + quad * 4;
        bool diag = (kt == qb);
        float rmax[4] = {-1e30f, -1e30f, -1e30f, -1e30f};
        for (int jt = 0; jt < 4; jt++) {
            int key = k0 + jt * 16 + l16;
            for (int r = 0; r < 4; r++) {
                float sv = s_acc[jt][r] * 0.125f;
                if (diag) sv = (key <= tq0 + r) ? sv : -1e30f;
                s_acc[jt][r] = sv;
                rmax[r] = fmaxf(rmax[r], sv);
            }
        }
        float alpha[4];
        for (int r = 0; r < 4; r++) {
            float m = rmax[r];
            m = fmaxf(m, __shfl_xor(m, 1));
            m = fmaxf(m, __shfl_xor(m, 2));
            m = fmaxf(m, __shfl_xor(m, 4));
            m = fmaxf(m, __shfl_xor(m, 8));
            float mnew = fmaxf(mrow[r], m);
            alpha[r] = __expf(mrow[r] - mnew);
            mrow[r] = mnew;
            lrow[r] *= alpha[r];
        }
        for (int jt = 0; jt < 4; jt++)
            for (int r = 0; r < 4; r++)
                o[jt][r] *= alpha[r];
        for (int r = 0; r < 4; r++) {
            float rsum = 0.f;
            for (int jt = 0; jt < 4; jt++) {
                float pv = __expf(s_acc[jt][r] - mrow[r]);
                s_acc[jt][r] = pv;
                rsum += pv;
            }
            rsum += __shfl_xor(rsum, 1);
            rsum += __shfl_xor(rsum, 2);
            rsum += __shfl_xor(rsum, 4);
            rsum += __shfl_xor(rsum, 8);
            lrow[r] += rsum;
        }
        for (int jt = 0; jt < 4; jt++)
            for (int r = 0; r < 4; r++)
                sP[wave][quad * 4 + r][jt * 16 + l16] = (__bf16)s_acc[jt][r];
        // sP is wave-private: compiler's lgkmcnt wait suffices, no barrier.

        // O += P V
        for (int kp = 0; kp < 2; kp++) {
            bf16x8 pf = *(const bf16x8*)&sP[wave][l16][kp * 32 + quad * 8];
            for (int jt2 = 0; jt2 < 4; jt2++) {
                int d = jt2 * 16 + l16;
                int pg = (kp * 4 + quad) ^ (d >> 3);
                bf16x8 vf = *(const bf16x8*)&sVt[d][pg * 8];
                o[jt2] = __builtin_amdgcn_mfma_f32_16x16x32_bf16(
                    pf, vf, o[jt2], 0, 0, 0);
            }
        }
    }

    float inv[4];
    for (int r = 0; r < 4; r++) inv[r] = __builtin_amdgcn_rcpf(lrow[r]);
    for (int jt2 = 0; jt2 < 4; jt2++) {
        for (int r = 0; r < 4; r++) {
            int tq  = qrow + quad * 4 + r;
            int col = h * HD + jt2 * 16 + l16;
            size_t gi = (rowbase + tq) * EMB + col;
            x2[gi] = x[gi] + o[jt2][r] * inv[r];
        }
    }
}

// ---------------------------------------------------------------------------
extern "C" void kernel_launch(void* const* d_in, const int* in_sizes, int n_in,
                              void* d_out, int out_size, void* d_ws, size_t ws_size,
                              hipStream_t stream) {
    const float* x      = (const float*)d_in[0];
    const float* ln1_s  = (const float*)d_in[1];
    const float* ln1_b  = (const float*)d_in[2];
    const float* w_qkv  = (const float*)d_in[3];
    const float* b_qkv  = (const float*)d_in[4];
    const float* ln2_s  = (const float*)d_in[5];
    const float* ln2_b  = (const float*)d_in[6];
    const float* w_fc   = (const float*)d_in[7];
    const float* b_fc   = (const float*)d_in[8];
    const float* w_proj = (const float*)d_in[9];
    const float* b_proj = (const float*)d_in[10];
    float* out = (float*)d_out;

    const int M = 2 * T_LEN;  // 4096 rows
    char* ws = (char*)d_ws;
    size_t off = 0;
    auto alloc = [&](size_t bytes) {
        void* p = ws + off; off += (bytes + 255) & ~(size_t)255; return p;
    };
    __bf16* wqkv_t = (__bf16*)alloc((size_t)3072 * 1024 * 2);
    __bf16* wfc_t  = (__bf16*)alloc((size_t)4096 * 1024 * 2);
    __bf16* wpj_t  = (__bf16*)alloc((size_t)1024 * 4096 * 2);
    __bf16* h1     = (__bf16*)alloc((size_t)M * 1024 * 2);
    __bf16* qkvb   = (__bf16*)alloc((size_t)M * 3072 * 2);
    float*  x2     = (float*) alloc((size_t)M * 1024 * 4);
    __bf16* h2     = (__bf16*)alloc((size_t)M * 1024 * 2);
    __bf16* hfc    = (__bf16*)alloc((size_t)M * 4096 * 2);

    dim3 tb(32, 8);
    transpose_cast<<<dim3(3072 / 32, 1024 / 32), tb, 0, stream>>>(w_qkv, wqkv_t, 1024, 3072);
    transpose_cast<<<dim3(4096 / 32, 1024 / 32), tb, 0, stream>>>(w_fc,  wfc_t,  1024, 4096);
    transpose_cast<<<dim3(1024 / 32, 4096 / 32), tb, 0, stream>>>(w_proj, wpj_t, 4096, 1024);

    ln_kernel<<<M, 256, 0, stream>>>(x, ln1_s, ln1_b, h1);

    gemm_bt<<<dim3(3072 / 128, M / 128), 256, 0, stream>>>(
        h1, wqkv_t, b_qkv, nullptr, nullptr, qkvb, M, 3072, 1024, 0);

    attn_kernel<<<dim3(32, 2 * NH), 256, 0, stream>>>(qkvb, x, x2);

    ln_kernel<<<M, 256, 0, stream>>>(x2, ln2_s, ln2_b, h2);

    gemm_bt<<<dim3(4096 / 128, M / 128), 256, 0, stream>>>(
        h2, wfc_t, b_fc, nullptr, nullptr, hfc, M, 4096, 1024, 1);

    gemm_bt<<<dim3(1024 / 128, M / 128), 256, 0, stream>>>(
        hfc, wpj_t, b_proj, x2, out, nullptr, M, 1024, 4096, 0);
}

// Round 3
// 430.394 us; speedup vs baseline: 1.1685x; 1.0432x over previous
//
#include <hip/hip_runtime.h>
#include <hip/hip_bf16.h>

// ---------------------------------------------------------------------------
// Transformer block: x + attn(LN1(x)) ; then x2 + proj(relu(fc(LN2(x2))))
// B=2, T=2048, C=1024, H=16, hd=64, MLP hidden 4096. All GEMMs bf16 MFMA.
// R3: attn gets register-prefetched K/V staging (hide global latency),
//     exp2-domain softmax (scale folded into Q), row-sum via ones-MFMA,
//     conditional rescale. GEMMs unchanged (global_load_lds m97 pattern).
// ---------------------------------------------------------------------------

typedef __bf16  bf16x8  __attribute__((ext_vector_type(8)));
typedef float   floatx4 __attribute__((ext_vector_type(4)));

#define T_LEN 2048
#define EMB   1024
#define NH    16
#define HD    64
#define HID   4096

#define GLOBAL_LOAD_LDS16(gp, lp) \
    __builtin_amdgcn_global_load_lds( \
        (const __attribute__((address_space(1))) void*)(gp), \
        (__attribute__((address_space(3))) void*)(lp), 16, 0, 0)

// ---------------- transpose + cast: in fp32 [R,C] -> out bf16 [C,R] --------
__global__ void transpose_cast(const float* __restrict__ in,
                               __bf16* __restrict__ out, int R, int C) {
    __shared__ float tile[32][33];
    int bc = blockIdx.x * 32;
    int br = blockIdx.y * 32;
    int tx = threadIdx.x;
    int ty = threadIdx.y;
    for (int i = 0; i < 32; i += 8) {
        tile[ty + i][tx] = in[(size_t)(br + ty + i) * C + bc + tx];
    }
    __syncthreads();
    for (int i = 0; i < 32; i += 8) {
        int c = bc + ty + i, r = br + tx;
        out[(size_t)c * R + r] = (__bf16)tile[tx][ty + i];
    }
}

// ---------------- layernorm fp32 [M,1024] -> bf16 [M,1024] -----------------
__global__ __launch_bounds__(256)
void ln_kernel(const float* __restrict__ in, const float* __restrict__ sc,
               const float* __restrict__ sh, __bf16* __restrict__ out) {
    int row = blockIdx.x;
    const float* p = in + (size_t)row * EMB;
    int tid = threadIdx.x;
    int lane = tid & 63, wave = tid >> 6;
    float v[4];
    float s = 0.f, s2 = 0.f;
    for (int j = 0; j < 4; j++) {
        v[j] = p[tid + j * 256];
        s += v[j]; s2 += v[j] * v[j];
    }
    for (int m = 1; m < 64; m <<= 1) {
        s  += __shfl_xor(s, m);
        s2 += __shfl_xor(s2, m);
    }
    __shared__ float ssum[4], ssum2[4];
    if (lane == 0) { ssum[wave] = s; ssum2[wave] = s2; }
    __syncthreads();
    float tot  = ssum[0] + ssum[1] + ssum[2] + ssum[3];
    float tot2 = ssum2[0] + ssum2[1] + ssum2[2] + ssum2[3];
    float mean = tot * (1.f / EMB);
    float var  = tot2 * (1.f / EMB) - mean * mean;
    float rstd = rsqrtf(var + 1e-5f);
    for (int j = 0; j < 4; j++) {
        int c = tid + j * 256;
        out[(size_t)row * EMB + c] = (__bf16)((v[j] - mean) * rstd * sc[c] + sh[c]);
    }
}

// ---------------- bf16 MFMA GEMM: C = A[M,K] @ Bt[N,K]^T + bias ------------
__global__ __launch_bounds__(256)
void gemm_bt(const __bf16* __restrict__ A, const __bf16* __restrict__ Bt,
             const float* __restrict__ bias, const float* __restrict__ res,
             float* __restrict__ outF, __bf16* __restrict__ outB,
             int M, int N, int K, int relu) {
    __shared__ __align__(16) __bf16 sA[128][32];
    __shared__ __align__(16) __bf16 sB[128][32];
    int tid  = threadIdx.x;
    int lane = tid & 63, wave = tid >> 6;
    int quad = lane >> 4, l16 = lane & 15;
    int bm = blockIdx.y * 128, bn = blockIdx.x * 128;
    int wm = (wave & 1) * 64, wn = (wave >> 1) * 64;
    floatx4 acc[4][4] = {};

    int seg = wave * 2;
    int srow = seg * 16 + (lane >> 2);
    int scol = (lane & 3) * 8;
    const __bf16* gA0 = &A[(size_t)(bm + srow) * K + scol];
    const __bf16* gB0 = &Bt[(size_t)(bn + srow) * K + scol];
    __bf16* lA0 = &sA[seg * 16][0];
    __bf16* lB0 = &sB[seg * 16][0];

    for (int kk = 0; kk < K; kk += 32) {
        __syncthreads();
        GLOBAL_LOAD_LDS16(gA0 + kk, lA0);
        GLOBAL_LOAD_LDS16(gA0 + kk + (size_t)16 * K, lA0 + 16 * 32);
        GLOBAL_LOAD_LDS16(gB0 + kk, lB0);
        GLOBAL_LOAD_LDS16(gB0 + kk + (size_t)16 * K, lB0 + 16 * 32);
        __syncthreads();
        bf16x8 af[4], bfr[4];
        for (int i = 0; i < 4; i++)
            af[i] = *(const bf16x8*)&sA[wm + i * 16 + l16][quad * 8];
        for (int j = 0; j < 4; j++)
            bfr[j] = *(const bf16x8*)&sB[wn + j * 16 + l16][quad * 8];
        for (int i = 0; i < 4; i++)
            for (int j = 0; j < 4; j++)
                acc[i][j] = __builtin_amdgcn_mfma_f32_16x16x32_bf16(
                    af[i], bfr[j], acc[i][j], 0, 0, 0);
    }

    for (int i = 0; i < 4; i++) {
        int row0 = bm + wm + i * 16 + quad * 4;
        for (int j = 0; j < 4; j++) {
            int col = bn + wn + j * 16 + l16;
            float bv = bias[col];
            for (int r = 0; r < 4; r++) {
                size_t idx = (size_t)(row0 + r) * N + col;
                float c = acc[i][j][r] + bv;
                if (relu) c = fmaxf(c, 0.f);
                if (res)  c += res[idx];
                if (outF) outF[idx] = c;
                if (outB) outB[idx] = (__bf16)c;
            }
        }
    }
}

// ---------------- flash attention ------------------------------------------
// qkv bf16 [B*T, 3072]; out x2 = x + attn_out (fp32).
// grid: (32 qtiles, B*NH), block 256; wave = 16 q-rows; KV tiles of 64.
// Softmax in exp2 domain: Q pre-scaled by 0.125*log2(e).
// Row-sum l accumulated via ones-column MFMA (rescales with o uniformly).
__global__ __launch_bounds__(256)
void attn_kernel(const __bf16* __restrict__ qkv, const float* __restrict__ x,
                 float* __restrict__ x2) {
    __shared__ __align__(16) __bf16 sK[64][72];
    __shared__ __align__(16) __bf16 sVt[64][72];
    __shared__ __align__(16) __bf16 sP[4][16][72];
    const int tid  = threadIdx.x;
    const int lane = tid & 63, wave = tid >> 6;
    const int quad = lane >> 4, l16 = lane & 15;
    const int qx = blockIdx.x;
    const int qb = (qx & 1) ? (31 - (qx >> 1)) : (qx >> 1);   // load balance
    const int bh = blockIdx.y;
    const int h  = bh & (NH - 1);
    const int b  = bh >> 4;
    const size_t rowbase = (size_t)b * T_LEN;
    const int qrow = qb * 64 + wave * 16;

    // Q fragments pre-scaled so S arrives in exp2 domain.
    const float kQScale = 0.125f * 1.44269504088896f;
    bf16x8 qf[2];
    for (int ks = 0; ks < 2; ks++) {
        bf16x8 raw = *(const bf16x8*)&qkv[(rowbase + qrow + l16) * 3072
                                          + h * HD + ks * 32 + quad * 8];
        for (int j = 0; j < 8; j++) qf[ks][j] = (__bf16)((float)raw[j] * kQScale);
    }
    bf16x8 ones;
    for (int j = 0; j < 8; j++) ones[j] = (__bf16)1.0f;

    floatx4 o[4] = {}, ol = {};
    float mrow[4];
    for (int r = 0; r < 4; r++) mrow[r] = -1e30f;

    // staging units: thread covers keys key0 and key0+32, 8 dims each
    const int key0 = tid >> 3, m8 = tid & 7;
    const int key1 = key0 + 32;
    const __bf16* kp0 = qkv + (rowbase + key0) * 3072 + h * HD + m8 * 8 + 1024;
    const __bf16* kp1 = qkv + (rowbase + key1) * 3072 + h * HD + m8 * 8 + 1024;
    const int pc0 = ((key0 >> 3) ^ m8) * 8 + (key0 & 7);
    const int pc1 = ((key1 >> 3) ^ m8) * 8 + (key1 & 7);

    // prologue: tile 0 into registers
    uint4 kr0 = *(const uint4*)kp0;
    uint4 kr1 = *(const uint4*)kp1;
    uint4 vr0 = *(const uint4*)(kp0 + 1024);
    uint4 vr1 = *(const uint4*)(kp1 + 1024);

    const int ntiles = qb + 1;
    for (int kt = 0; kt < ntiles; kt++) {
        __syncthreads();   // prior iter's sK/sVt reads done
        *(uint4*)&sK[key0][m8 * 8] = kr0;
        *(uint4*)&sK[key1][m8 * 8] = kr1;
        {
            bf16x8 v0 = *(bf16x8*)&vr0, v1 = *(bf16x8*)&vr1;
            for (int j = 0; j < 8; j++) sVt[m8 * 8 + j][pc0] = v0[j];
            for (int j = 0; j < 8; j++) sVt[m8 * 8 + j][pc1] = v1[j];
        }
        // prefetch next tile (clamped on last iter); vmcnt waits land after
        // compute, so global latency overlaps QK/softmax/PV.
        {
            size_t offn = (size_t)((kt + 1 < ntiles) ? kt + 1 : kt) * (64 * 3072);
            kr0 = *(const uint4*)(kp0 + offn);
            kr1 = *(const uint4*)(kp1 + offn);
            vr0 = *(const uint4*)(kp0 + offn + 1024);
            vr1 = *(const uint4*)(kp1 + offn + 1024);
        }
        __syncthreads();

        // S = Q K^T (exp2 domain)
        floatx4 s_acc[4] = {};
        for (int jt = 0; jt < 4; jt++)
            for (int ks = 0; ks < 2; ks++) {
                bf16x8 kf = *(const bf16x8*)&sK[jt * 16 + l16][ks * 32 + quad * 8];
                s_acc[jt] = __builtin_amdgcn_mfma_f32_16x16x32_bf16(
                    qf[ks], kf, s_acc[jt], 0, 0, 0);
            }

        const int tq0 = qrow + quad * 4;
        const int k0 = kt * 64;
        float rmax[4] = {-1e30f, -1e30f, -1e30f, -1e30f};
        if (kt == qb) {   // only the diagonal tile needs masking
            for (int jt = 0; jt < 4; jt++) {
                int key = k0 + jt * 16 + l16;
                for (int r = 0; r < 4; r++) {
                    float sv = (key <= tq0 + r) ? s_acc[jt][r] : -1e30f;
                    s_acc[jt][r] = sv;
                    rmax[r] = fmaxf(rmax[r], sv);
                }
            }
        } else {
            for (int jt = 0; jt < 4; jt++)
                for (int r = 0; r < 4; r++)
                    rmax[r] = fmaxf(rmax[r], s_acc[jt][r]);
        }

        bool changed = false;
        float mnew[4];
        for (int r = 0; r < 4; r++) {
            float m = rmax[r];
            m = fmaxf(m, __shfl_xor(m, 1));
            m = fmaxf(m, __shfl_xor(m, 2));
            m = fmaxf(m, __shfl_xor(m, 4));
            m = fmaxf(m, __shfl_xor(m, 8));
            mnew[r] = fmaxf(mrow[r], m);
            changed |= (mnew[r] > mrow[r]);
        }
        if (__any(changed)) {   // rescale only when the running max moved
            for (int r = 0; r < 4; r++) {
                float alpha = __builtin_amdgcn_exp2f(mrow[r] - mnew[r]);
                mrow[r] = mnew[r];
                ol[r] *= alpha;
                for (int jt = 0; jt < 4; jt++) o[jt][r] *= alpha;
            }
        }

        for (int jt = 0; jt < 4; jt++)
            for (int r = 0; r < 4; r++) {
                float pv = __builtin_amdgcn_exp2f(s_acc[jt][r] - mrow[r]);
                sP[wave][quad * 4 + r][jt * 16 + l16] = (__bf16)pv;
            }
        // sP is wave-private: compiler lgkmcnt ordering suffices, no barrier.

        // O += P V ; l += P 1  (ones-column MFMA replaces shuffle row-sum)
        for (int kp = 0; kp < 2; kp++) {
            bf16x8 pf = *(const bf16x8*)&sP[wave][l16][kp * 32 + quad * 8];
            ol = __builtin_amdgcn_mfma_f32_16x16x32_bf16(pf, ones, ol, 0, 0, 0);
            for (int jt2 = 0; jt2 < 4; jt2++) {
                int d = jt2 * 16 + l16;
                int pg = (kp * 4 + quad) ^ (d >> 3);
                bf16x8 vf = *(const bf16x8*)&sVt[d][pg * 8];
                o[jt2] = __builtin_amdgcn_mfma_f32_16x16x32_bf16(
                    pf, vf, o[jt2], 0, 0, 0);
            }
        }
    }

    float inv[4];
    for (int r = 0; r < 4; r++) inv[r] = __builtin_amdgcn_rcpf(ol[r]);
    for (int jt2 = 0; jt2 < 4; jt2++) {
        for (int r = 0; r < 4; r++) {
            int tq  = qrow + quad * 4 + r;
            int col = h * HD + jt2 * 16 + l16;
            size_t gi = (rowbase + tq) * EMB + col;
            x2[gi] = x[gi] + o[jt2][r] * inv[r];
        }
    }
}

// ---------------------------------------------------------------------------
extern "C" void kernel_launch(void* const* d_in, const int* in_sizes, int n_in,
                              void* d_out, int out_size, void* d_ws, size_t ws_size,
                              hipStream_t stream) {
    const float* x      = (const float*)d_in[0];
    const float* ln1_s  = (const float*)d_in[1];
    const float* ln1_b  = (const float*)d_in[2];
    const float* w_qkv  = (const float*)d_in[3];
    const float* b_qkv  = (const float*)d_in[4];
    const float* ln2_s  = (const float*)d_in[5];
    const float* ln2_b  = (const float*)d_in[6];
    const float* w_fc   = (const float*)d_in[7];
    const float* b_fc   = (const float*)d_in[8];
    const float* w_proj = (const float*)d_in[9];
    const float* b_proj = (const float*)d_in[10];
    float* out = (float*)d_out;

    const int M = 2 * T_LEN;  // 4096 rows
    char* ws = (char*)d_ws;
    size_t off = 0;
    auto alloc = [&](size_t bytes) {
        void* p = ws + off; off += (bytes + 255) & ~(size_t)255; return p;
    };
    __bf16* wqkv_t = (__bf16*)alloc((size_t)3072 * 1024 * 2);
    __bf16* wfc_t  = (__bf16*)alloc((size_t)4096 * 1024 * 2);
    __bf16* wpj_t  = (__bf16*)alloc((size_t)1024 * 4096 * 2);
    __bf16* h1     = (__bf16*)alloc((size_t)M * 1024 * 2);
    __bf16* qkvb   = (__bf16*)alloc((size_t)M * 3072 * 2);
    float*  x2     = (float*) alloc((size_t)M * 1024 * 4);
    __bf16* h2     = (__bf16*)alloc((size_t)M * 1024 * 2);
    __bf16* hfc    = (__bf16*)alloc((size_t)M * 4096 * 2);

    dim3 tb(32, 8);
    transpose_cast<<<dim3(3072 / 32, 1024 / 32), tb, 0, stream>>>(w_qkv, wqkv_t, 1024, 3072);
    transpose_cast<<<dim3(4096 / 32, 1024 / 32), tb, 0, stream>>>(w_fc,  wfc_t,  1024, 4096);
    transpose_cast<<<dim3(1024 / 32, 4096 / 32), tb, 0, stream>>>(w_proj, wpj_t, 4096, 1024);

    ln_kernel<<<M, 256, 0, stream>>>(x, ln1_s, ln1_b, h1);

    gemm_bt<<<dim3(3072 / 128, M / 128), 256, 0, stream>>>(
        h1, wqkv_t, b_qkv, nullptr, nullptr, qkvb, M, 3072, 1024, 0);

    attn_kernel<<<dim3(32, 2 * NH), 256, 0, stream>>>(qkvb, x, x2);

    ln_kernel<<<M, 256, 0, stream>>>(x2, ln2_s, ln2_b, h2);

    gemm_bt<<<dim3(4096 / 128, M / 128), 256, 0, stream>>>(
        h2, wfc_t, b_fc, nullptr, nullptr, hfc, M, 4096, 1024, 1);

    gemm_bt<<<dim3(1024 / 128, M / 128), 256, 0, stream>>>(
        hfc, wpj_t, b_proj, x2, out, nullptr, M, 1024, 4096, 0);
}

// Round 4
// 374.433 us; speedup vs baseline: 1.3431x; 1.1495x over previous
//
#include <hip/hip_runtime.h>
#include <hip/hip_bf16.h>

// ---------------------------------------------------------------------------
// Transformer block: x + attn(LN1(x)) ; then x2 + proj(relu(fc(LN2(x2))))
// B=2, T=2048, C=1024, H=16, hd=64, MLP hidden 4096. All GEMMs bf16 MFMA.
// R4: attn prefetch issued AFTER 2nd barrier (vmcnt drain overlaps compute),
//     blocks process q-tile pair {x, 31-x} (exactly 33 iters each, grid 16x32);
//     proj gemm gets BN=64 variant (512 blocks instead of 256).
// ---------------------------------------------------------------------------

typedef __bf16  bf16x8  __attribute__((ext_vector_type(8)));
typedef float   floatx4 __attribute__((ext_vector_type(4)));

#define T_LEN 2048
#define EMB   1024
#define NH    16
#define HD    64
#define HID   4096

#define GLOBAL_LOAD_LDS16(gp, lp) \
    __builtin_amdgcn_global_load_lds( \
        (const __attribute__((address_space(1))) void*)(gp), \
        (__attribute__((address_space(3))) void*)(lp), 16, 0, 0)

// ---------------- transpose + cast: in fp32 [R,C] -> out bf16 [C,R] --------
__global__ void transpose_cast(const float* __restrict__ in,
                               __bf16* __restrict__ out, int R, int C) {
    __shared__ float tile[32][33];
    int bc = blockIdx.x * 32;
    int br = blockIdx.y * 32;
    int tx = threadIdx.x;
    int ty = threadIdx.y;
    for (int i = 0; i < 32; i += 8) {
        tile[ty + i][tx] = in[(size_t)(br + ty + i) * C + bc + tx];
    }
    __syncthreads();
    for (int i = 0; i < 32; i += 8) {
        int c = bc + ty + i, r = br + tx;
        out[(size_t)c * R + r] = (__bf16)tile[tx][ty + i];
    }
}

// ---------------- layernorm fp32 [M,1024] -> bf16 [M,1024] -----------------
__global__ __launch_bounds__(256)
void ln_kernel(const float* __restrict__ in, const float* __restrict__ sc,
               const float* __restrict__ sh, __bf16* __restrict__ out) {
    int row = blockIdx.x;
    const float* p = in + (size_t)row * EMB;
    int tid = threadIdx.x;
    int lane = tid & 63, wave = tid >> 6;
    float v[4];
    float s = 0.f, s2 = 0.f;
    for (int j = 0; j < 4; j++) {
        v[j] = p[tid + j * 256];
        s += v[j]; s2 += v[j] * v[j];
    }
    for (int m = 1; m < 64; m <<= 1) {
        s  += __shfl_xor(s, m);
        s2 += __shfl_xor(s2, m);
    }
    __shared__ float ssum[4], ssum2[4];
    if (lane == 0) { ssum[wave] = s; ssum2[wave] = s2; }
    __syncthreads();
    float tot  = ssum[0] + ssum[1] + ssum[2] + ssum[3];
    float tot2 = ssum2[0] + ssum2[1] + ssum2[2] + ssum2[3];
    float mean = tot * (1.f / EMB);
    float var  = tot2 * (1.f / EMB) - mean * mean;
    float rstd = rsqrtf(var + 1e-5f);
    for (int j = 0; j < 4; j++) {
        int c = tid + j * 256;
        out[(size_t)row * EMB + c] = (__bf16)((v[j] - mean) * rstd * sc[c] + sh[c]);
    }
}

// ---------------- bf16 MFMA GEMM (BM=128, BN=128) --------------------------
__global__ __launch_bounds__(256)
void gemm_bt(const __bf16* __restrict__ A, const __bf16* __restrict__ Bt,
             const float* __restrict__ bias, const float* __restrict__ res,
             float* __restrict__ outF, __bf16* __restrict__ outB,
             int M, int N, int K, int relu) {
    __shared__ __align__(16) __bf16 sA[128][32];
    __shared__ __align__(16) __bf16 sB[128][32];
    int tid  = threadIdx.x;
    int lane = tid & 63, wave = tid >> 6;
    int quad = lane >> 4, l16 = lane & 15;
    int bm = blockIdx.y * 128, bn = blockIdx.x * 128;
    int wm = (wave & 1) * 64, wn = (wave >> 1) * 64;
    floatx4 acc[4][4] = {};

    int seg = wave * 2;
    int srow = seg * 16 + (lane >> 2);
    int scol = (lane & 3) * 8;
    const __bf16* gA0 = &A[(size_t)(bm + srow) * K + scol];
    const __bf16* gB0 = &Bt[(size_t)(bn + srow) * K + scol];
    __bf16* lA0 = &sA[seg * 16][0];
    __bf16* lB0 = &sB[seg * 16][0];

    for (int kk = 0; kk < K; kk += 32) {
        __syncthreads();
        GLOBAL_LOAD_LDS16(gA0 + kk, lA0);
        GLOBAL_LOAD_LDS16(gA0 + kk + (size_t)16 * K, lA0 + 16 * 32);
        GLOBAL_LOAD_LDS16(gB0 + kk, lB0);
        GLOBAL_LOAD_LDS16(gB0 + kk + (size_t)16 * K, lB0 + 16 * 32);
        __syncthreads();
        bf16x8 af[4], bfr[4];
        for (int i = 0; i < 4; i++)
            af[i] = *(const bf16x8*)&sA[wm + i * 16 + l16][quad * 8];
        for (int j = 0; j < 4; j++)
            bfr[j] = *(const bf16x8*)&sB[wn + j * 16 + l16][quad * 8];
        for (int i = 0; i < 4; i++)
            for (int j = 0; j < 4; j++)
                acc[i][j] = __builtin_amdgcn_mfma_f32_16x16x32_bf16(
                    af[i], bfr[j], acc[i][j], 0, 0, 0);
    }

    for (int i = 0; i < 4; i++) {
        int row0 = bm + wm + i * 16 + quad * 4;
        for (int j = 0; j < 4; j++) {
            int col = bn + wn + j * 16 + l16;
            float bv = bias[col];
            for (int r = 0; r < 4; r++) {
                size_t idx = (size_t)(row0 + r) * N + col;
                float c = acc[i][j][r] + bv;
                if (relu) c = fmaxf(c, 0.f);
                if (res)  c += res[idx];
                if (outF) outF[idx] = c;
                if (outB) outB[idx] = (__bf16)c;
            }
        }
    }
}

// ---------------- bf16 MFMA GEMM (BM=128, BN=64) for narrow-N shapes -------
__global__ __launch_bounds__(256)
void gemm_bt_n64(const __bf16* __restrict__ A, const __bf16* __restrict__ Bt,
                 const float* __restrict__ bias, const float* __restrict__ res,
                 float* __restrict__ outF, __bf16* __restrict__ outB,
                 int M, int N, int K, int relu) {
    __shared__ __align__(16) __bf16 sA[128][32];
    __shared__ __align__(16) __bf16 sB[64][32];
    int tid  = threadIdx.x;
    int lane = tid & 63, wave = tid >> 6;
    int quad = lane >> 4, l16 = lane & 15;
    int bm = blockIdx.y * 128, bn = blockIdx.x * 64;
    int wm = (wave & 1) * 64, wn = (wave >> 1) * 32;
    floatx4 acc[4][2] = {};

    // staging: wave covers sA rows [32w,32w+32) (2 loads) + sB rows [16w,16w+16)
    int srowA = wave * 32 + (lane >> 2);
    int srowB = wave * 16 + (lane >> 2);
    int scol  = (lane & 3) * 8;
    const __bf16* gA0 = &A[(size_t)(bm + srowA) * K + scol];
    const __bf16* gB0 = &Bt[(size_t)(bn + srowB) * K + scol];
    __bf16* lA0 = &sA[wave * 32][0];
    __bf16* lB0 = &sB[wave * 16][0];

    for (int kk = 0; kk < K; kk += 32) {
        __syncthreads();
        GLOBAL_LOAD_LDS16(gA0 + kk, lA0);
        GLOBAL_LOAD_LDS16(gA0 + kk + (size_t)16 * K, lA0 + 16 * 32);
        GLOBAL_LOAD_LDS16(gB0 + kk, lB0);
        __syncthreads();
        bf16x8 af[4], bfr[2];
        for (int i = 0; i < 4; i++)
            af[i] = *(const bf16x8*)&sA[wm + i * 16 + l16][quad * 8];
        for (int j = 0; j < 2; j++)
            bfr[j] = *(const bf16x8*)&sB[wn + j * 16 + l16][quad * 8];
        for (int i = 0; i < 4; i++)
            for (int j = 0; j < 2; j++)
                acc[i][j] = __builtin_amdgcn_mfma_f32_16x16x32_bf16(
                    af[i], bfr[j], acc[i][j], 0, 0, 0);
    }

    for (int i = 0; i < 4; i++) {
        int row0 = bm + wm + i * 16 + quad * 4;
        for (int j = 0; j < 2; j++) {
            int col = bn + wn + j * 16 + l16;
            float bv = bias[col];
            for (int r = 0; r < 4; r++) {
                size_t idx = (size_t)(row0 + r) * N + col;
                float c = acc[i][j][r] + bv;
                if (relu) c = fmaxf(c, 0.f);
                if (res)  c += res[idx];
                if (outF) outF[idx] = c;
                if (outB) outB[idx] = (__bf16)c;
            }
        }
    }
}

// ---------------- flash attention ------------------------------------------
// Each block handles q-tiles {x, 31-x} sequentially: exactly 33 KV-tile
// iterations per block. Prefetch issued after 2nd barrier so its vmcnt
// drain (at next loop-top barrier) overlaps the compute phase.
__global__ __launch_bounds__(256)
void attn_kernel(const __bf16* __restrict__ qkv, const float* __restrict__ x,
                 float* __restrict__ x2) {
    __shared__ __align__(16) __bf16 sK[64][72];
    __shared__ __align__(16) __bf16 sVt[64][72];
    __shared__ __align__(16) __bf16 sP[4][16][72];
    const int tid  = threadIdx.x;
    const int lane = tid & 63, wave = tid >> 6;
    const int quad = lane >> 4, l16 = lane & 15;
    const int xpair = blockIdx.x;         // 0..15
    const int bh = blockIdx.y;
    const int h  = bh & (NH - 1);
    const int b  = bh >> 4;
    const size_t rowbase = (size_t)b * T_LEN;

    const float kQScale = 0.125f * 1.44269504088896f;
    bf16x8 ones;
    for (int j = 0; j < 8; j++) ones[j] = (__bf16)1.0f;

    // staging constants: thread covers keys key0, key0+32 (8 dims each)
    const int key0 = tid >> 3, m8 = tid & 7;
    const int key1 = key0 + 32;
    const __bf16* kp0 = qkv + (rowbase + key0) * 3072 + h * HD + m8 * 8 + 1024;
    const __bf16* kp1 = qkv + (rowbase + key1) * 3072 + h * HD + m8 * 8 + 1024;
    const int pc0 = ((key0 >> 3) ^ m8) * 8 + (key0 & 7);
    const int pc1 = ((key1 >> 3) ^ m8) * 8 + (key1 & 7);

    for (int ph = 0; ph < 2; ph++) {
        const int qb = ph ? (31 - xpair) : xpair;
        const int qrow = qb * 64 + wave * 16;

        bf16x8 qf[2];
        for (int ks = 0; ks < 2; ks++) {
            bf16x8 raw = *(const bf16x8*)&qkv[(rowbase + qrow + l16) * 3072
                                              + h * HD + ks * 32 + quad * 8];
            for (int j = 0; j < 8; j++)
                qf[ks][j] = (__bf16)((float)raw[j] * kQScale);
        }

        floatx4 o[4] = {}, ol = {};
        float mrow[4];
        for (int r = 0; r < 4; r++) mrow[r] = -1e30f;

        // prologue: tile 0 into registers
        uint4 kr0 = *(const uint4*)kp0;
        uint4 kr1 = *(const uint4*)kp1;
        uint4 vr0 = *(const uint4*)(kp0 + 1024);
        uint4 vr1 = *(const uint4*)(kp1 + 1024);

        const int ntiles = qb + 1;
        for (int kt = 0; kt < ntiles; kt++) {
            __syncthreads();   // prior reads done + drains prefetch vmcnt
            *(uint4*)&sK[key0][m8 * 8] = kr0;
            *(uint4*)&sK[key1][m8 * 8] = kr1;
            {
                bf16x8 v0 = *(bf16x8*)&vr0, v1 = *(bf16x8*)&vr1;
                for (int j = 0; j < 8; j++) sVt[m8 * 8 + j][pc0] = v0[j];
                for (int j = 0; j < 8; j++) sVt[m8 * 8 + j][pc1] = v1[j];
            }
            __syncthreads();

            // prefetch next tile AFTER the barrier: its vmcnt(0) drain lands
            // at the next loop-top barrier, overlapping all compute below.
            {
                size_t offn = (size_t)((kt + 1 < ntiles) ? kt + 1 : kt)
                              * (64 * 3072);
                kr0 = *(const uint4*)(kp0 + offn);
                kr1 = *(const uint4*)(kp1 + offn);
                vr0 = *(const uint4*)(kp0 + offn + 1024);
                vr1 = *(const uint4*)(kp1 + offn + 1024);
            }

            // S = Q K^T (exp2 domain)
            floatx4 s_acc[4] = {};
            for (int jt = 0; jt < 4; jt++)
                for (int ks = 0; ks < 2; ks++) {
                    bf16x8 kf = *(const bf16x8*)&sK[jt * 16 + l16]
                                                  [ks * 32 + quad * 8];
                    s_acc[jt] = __builtin_amdgcn_mfma_f32_16x16x32_bf16(
                        qf[ks], kf, s_acc[jt], 0, 0, 0);
                }

            const int tq0 = qrow + quad * 4;
            const int k0 = kt * 64;
            float rmax[4] = {-1e30f, -1e30f, -1e30f, -1e30f};
            if (kt == qb) {   // only diagonal tile needs masking
                for (int jt = 0; jt < 4; jt++) {
                    int key = k0 + jt * 16 + l16;
                    for (int r = 0; r < 4; r++) {
                        float sv = (key <= tq0 + r) ? s_acc[jt][r] : -1e30f;
                        s_acc[jt][r] = sv;
                        rmax[r] = fmaxf(rmax[r], sv);
                    }
                }
            } else {
                for (int jt = 0; jt < 4; jt++)
                    for (int r = 0; r < 4; r++)
                        rmax[r] = fmaxf(rmax[r], s_acc[jt][r]);
            }

            bool changed = false;
            float mnew[4];
            for (int r = 0; r < 4; r++) {
                float m = rmax[r];
                m = fmaxf(m, __shfl_xor(m, 1));
                m = fmaxf(m, __shfl_xor(m, 2));
                m = fmaxf(m, __shfl_xor(m, 4));
                m = fmaxf(m, __shfl_xor(m, 8));
                mnew[r] = fmaxf(mrow[r], m);
                changed |= (mnew[r] > mrow[r]);
            }
            if (__any(changed)) {
                for (int r = 0; r < 4; r++) {
                    float alpha = __builtin_amdgcn_exp2f(mrow[r] - mnew[r]);
                    mrow[r] = mnew[r];
                    ol[r] *= alpha;
                    for (int jt = 0; jt < 4; jt++) o[jt][r] *= alpha;
                }
            }

            for (int jt = 0; jt < 4; jt++)
                for (int r = 0; r < 4; r++) {
                    float pv = __builtin_amdgcn_exp2f(s_acc[jt][r] - mrow[r]);
                    sP[wave][quad * 4 + r][jt * 16 + l16] = (__bf16)pv;
                }
            // sP is wave-private: lgkmcnt ordering suffices, no barrier.

            for (int kp = 0; kp < 2; kp++) {
                bf16x8 pf = *(const bf16x8*)&sP[wave][l16][kp * 32 + quad * 8];
                ol = __builtin_amdgcn_mfma_f32_16x16x32_bf16(pf, ones, ol,
                                                             0, 0, 0);
                for (int jt2 = 0; jt2 < 4; jt2++) {
                    int d = jt2 * 16 + l16;
                    int pg = (kp * 4 + quad) ^ (d >> 3);
                    bf16x8 vf = *(const bf16x8*)&sVt[d][pg * 8];
                    o[jt2] = __builtin_amdgcn_mfma_f32_16x16x32_bf16(
                        pf, vf, o[jt2], 0, 0, 0);
                }
            }
        }

        float inv[4];
        for (int r = 0; r < 4; r++) inv[r] = __builtin_amdgcn_rcpf(ol[r]);
        for (int jt2 = 0; jt2 < 4; jt2++) {
            for (int r = 0; r < 4; r++) {
                int tq  = qrow + quad * 4 + r;
                int col = h * HD + jt2 * 16 + l16;
                size_t gi = (rowbase + tq) * EMB + col;
                x2[gi] = x[gi] + o[jt2][r] * inv[r];
            }
        }
    }
}

// ---------------------------------------------------------------------------
extern "C" void kernel_launch(void* const* d_in, const int* in_sizes, int n_in,
                              void* d_out, int out_size, void* d_ws, size_t ws_size,
                              hipStream_t stream) {
    const float* x      = (const float*)d_in[0];
    const float* ln1_s  = (const float*)d_in[1];
    const float* ln1_b  = (const float*)d_in[2];
    const float* w_qkv  = (const float*)d_in[3];
    const float* b_qkv  = (const float*)d_in[4];
    const float* ln2_s  = (const float*)d_in[5];
    const float* ln2_b  = (const float*)d_in[6];
    const float* w_fc   = (const float*)d_in[7];
    const float* b_fc   = (const float*)d_in[8];
    const float* w_proj = (const float*)d_in[9];
    const float* b_proj = (const float*)d_in[10];
    float* out = (float*)d_out;

    const int M = 2 * T_LEN;  // 4096 rows
    char* ws = (char*)d_ws;
    size_t off = 0;
    auto alloc = [&](size_t bytes) {
        void* p = ws + off; off += (bytes + 255) & ~(size_t)255; return p;
    };
    __bf16* wqkv_t = (__bf16*)alloc((size_t)3072 * 1024 * 2);
    __bf16* wfc_t  = (__bf16*)alloc((size_t)4096 * 1024 * 2);
    __bf16* wpj_t  = (__bf16*)alloc((size_t)1024 * 4096 * 2);
    __bf16* h1     = (__bf16*)alloc((size_t)M * 1024 * 2);
    __bf16* qkvb   = (__bf16*)alloc((size_t)M * 3072 * 2);
    float*  x2     = (float*) alloc((size_t)M * 1024 * 4);
    __bf16* h2     = (__bf16*)alloc((size_t)M * 1024 * 2);
    __bf16* hfc    = (__bf16*)alloc((size_t)M * 4096 * 2);

    dim3 tb(32, 8);
    transpose_cast<<<dim3(3072 / 32, 1024 / 32), tb, 0, stream>>>(w_qkv, wqkv_t, 1024, 3072);
    transpose_cast<<<dim3(4096 / 32, 1024 / 32), tb, 0, stream>>>(w_fc,  wfc_t,  1024, 4096);
    transpose_cast<<<dim3(1024 / 32, 4096 / 32), tb, 0, stream>>>(w_proj, wpj_t, 4096, 1024);

    ln_kernel<<<M, 256, 0, stream>>>(x, ln1_s, ln1_b, h1);

    gemm_bt<<<dim3(3072 / 128, M / 128), 256, 0, stream>>>(
        h1, wqkv_t, b_qkv, nullptr, nullptr, qkvb, M, 3072, 1024, 0);

    attn_kernel<<<dim3(16, 2 * NH), 256, 0, stream>>>(qkvb, x, x2);

    ln_kernel<<<M, 256, 0, stream>>>(x2, ln2_s, ln2_b, h2);

    gemm_bt<<<dim3(4096 / 128, M / 128), 256, 0, stream>>>(
        h2, wfc_t, b_fc, nullptr, nullptr, hfc, M, 4096, 1024, 1);

    gemm_bt_n64<<<dim3(1024 / 64, M / 128), 256, 0, stream>>>(
        hfc, wpj_t, b_proj, x2, out, nullptr, M, 1024, 4096, 0);
}